// Round 2
// baseline (743.882 us; speedup 1.0000x reference)
//
#include <hip/hip_runtime.h>
#include <hip/hip_bf16.h>

#define NATOM 50000
#define MNBR  32
#define NEDGE (NATOM * MNBR)   // 1,600,000 (divisible by 16)
#define ATOMF 128
#define NBRF  64
#define SHDIM 9

typedef float  f32x4  __attribute__((ext_vector_type(4)));
typedef __bf16 bf16x8 __attribute__((ext_vector_type(8)));

__device__ __forceinline__ float softplus_f(float x) {
    // jax.nn.softplus: max(x,0) + log1p(exp(-|x|))
    return fmaxf(x, 0.0f) + log1pf(__expf(-fabsf(x)));
}

__device__ __forceinline__ bf16x8 to_bf16x8(float4 lo, float4 hi) {
    bf16x8 r;
    r[0] = (__bf16)lo.x; r[1] = (__bf16)lo.y; r[2] = (__bf16)lo.z; r[3] = (__bf16)lo.w;
    r[4] = (__bf16)hi.x; r[5] = (__bf16)hi.y; r[6] = (__bf16)hi.z; r[7] = (__bf16)hi.w;
    return r;
}

// Edge kernel: per edge e, scalar_e = softplus(nbr_fea_e @ w1 + b1) . w2[:,0] + b2[0]
// scatter-add scalar_e into S[idx_e] and 1.0 into C[idx_e].
// One wave handles a tile of 16 edges via mfma_f32_16x16x32_bf16:
//   A (16 edges x K=64 radial) from global in native frag layout,
//   B (w1, 64x64) cached in registers for the kernel's lifetime.
__global__ __launch_bounds__(256, 4) void edge_kernel(
    const float* __restrict__ nbr_fea, const int* __restrict__ nbr_idx,
    const float* __restrict__ w1, const float* __restrict__ b1,
    const float* __restrict__ w2, const float* __restrict__ b2,
    float* __restrict__ S, float* __restrict__ C)
{
    const int lane = threadIdx.x & 63;
    const int m    = lane & 15;    // A-row / D-col index
    const int quad = lane >> 4;    // k-block / D-row-block index
    const int wave_id = (int)((blockIdx.x * blockDim.x + threadIdx.x) >> 6);
    const int nwaves  = (int)((gridDim.x * blockDim.x) >> 6);

    // B fragments: B[k][n] = w1[k][n]; lane holds k = c*32 + quad*8 + j, n = nb*16 + m
    bf16x8 bfrag[2][4];
#pragma unroll
    for (int c = 0; c < 2; ++c)
#pragma unroll
        for (int nb = 0; nb < 4; ++nb)
#pragma unroll
            for (int j = 0; j < 8; ++j)
                bfrag[c][nb][j] = (__bf16)w1[(c * 32 + quad * 8 + j) * NBRF + nb * 16 + m];

    float b1v[4], w2v[4];
#pragma unroll
    for (int nb = 0; nb < 4; ++nb) {
        b1v[nb] = b1[nb * 16 + m];
        w2v[nb] = w2[(nb * 16 + m) * SHDIM + 0];  // w2 is (64,9) row-major; col 0
    }
    const float b2_0 = b2[0];

    const int ntiles = NEDGE / 16;
    for (int t = wave_id; t < ntiles; t += nwaves) {
        const int e0 = t * 16;

        // A fragments: A[m][k], k = c*32 + quad*8 + j  -> two float4 loads per chunk
        bf16x8 afrag[2];
#pragma unroll
        for (int c = 0; c < 2; ++c) {
            const float* base = &nbr_fea[(size_t)(e0 + m) * NBRF + c * 32 + quad * 8];
            const float4 f0 = *(const float4*)(base);
            const float4 f1 = *(const float4*)(base + 4);
            afrag[c] = to_bf16x8(f0, f1);
        }

        f32x4 acc[4] = { {0.f,0.f,0.f,0.f}, {0.f,0.f,0.f,0.f},
                         {0.f,0.f,0.f,0.f}, {0.f,0.f,0.f,0.f} };
#pragma unroll
        for (int c = 0; c < 2; ++c)
#pragma unroll
            for (int nb = 0; nb < 4; ++nb)
                acc[nb] = __builtin_amdgcn_mfma_f32_16x16x32_bf16(
                    afrag[c], bfrag[c][nb], acc[nb], 0, 0, 0);

        // D layout: col(feature) = nb*16 + m, row(edge-local) = quad*4 + reg
        float part[4] = {0.f, 0.f, 0.f, 0.f};
#pragma unroll
        for (int nb = 0; nb < 4; ++nb)
#pragma unroll
            for (int r = 0; r < 4; ++r)
                part[r] += softplus_f(acc[nb][r] + b1v[nb]) * w2v[nb];

        // reduce over the 16 lanes of the quad (feature dimension)
#pragma unroll
        for (int off = 1; off < 16; off <<= 1)
#pragma unroll
            for (int r = 0; r < 4; ++r)
                part[r] += __shfl_xor(part[r], off, 64);

        if (m == 0) {
#pragma unroll
            for (int r = 0; r < 4; ++r) {
                const int e = e0 + quad * 4 + r;
                int j = nbr_idx[e];
                j = (j < 0) ? 0 : (j >= NATOM ? NATOM - 1 : j);  // never fault
                atomicAdd(&S[j], part[r] + b2_0);
                atomicAdd(&C[j], 1.0f);
            }
        }
    }
}

// Atom kernel: out[j][f] = (atom_fea[j] @ tp_w)[f] * S[j] / max(C[j],1) / sqrt(128)
// Block = 128 threads (one per output feature f), 16 atoms per block.
__global__ __launch_bounds__(128) void atom_kernel(
    const float* __restrict__ atom_fea, const float* __restrict__ tp_w,
    const float* __restrict__ S, const float* __restrict__ C,
    float* __restrict__ out)
{
    __shared__ __align__(16) float aT[ATOMF][20];  // [input-feature i][atom t], pad 16->20
    __shared__ float scale_s[16];

    const int f  = threadIdx.x;        // output feature
    const int j0 = blockIdx.x * 16;

    // stage 16 atoms transposed: aT[i][t] = atom_fea[j0+t][i]
#pragma unroll
    for (int it = 0; it < 16; ++it)
        aT[f][it] = atom_fea[(size_t)(j0 + it) * ATOMF + f];

    if (f < 16) {
        const float c = C[j0 + f];
        scale_s[f] = S[j0 + f] / fmaxf(c, 1.0f) * 0.08838834764831843f; // 1/sqrt(128)
    }
    __syncthreads();

    float acc[16];
#pragma unroll
    for (int t = 0; t < 16; ++t) acc[t] = 0.f;

    for (int i = 0; i < ATOMF; ++i) {
        const float w = tp_w[i * ATOMF + f];
        const float4 a0 = *(const float4*)&aT[i][0];
        const float4 a1 = *(const float4*)&aT[i][4];
        const float4 a2 = *(const float4*)&aT[i][8];
        const float4 a3 = *(const float4*)&aT[i][12];
        acc[0]  += a0.x * w; acc[1]  += a0.y * w; acc[2]  += a0.z * w; acc[3]  += a0.w * w;
        acc[4]  += a1.x * w; acc[5]  += a1.y * w; acc[6]  += a1.z * w; acc[7]  += a1.w * w;
        acc[8]  += a2.x * w; acc[9]  += a2.y * w; acc[10] += a2.z * w; acc[11] += a2.w * w;
        acc[12] += a3.x * w; acc[13] += a3.y * w; acc[14] += a3.z * w; acc[15] += a3.w * w;
    }

#pragma unroll
    for (int t = 0; t < 16; ++t)
        out[(size_t)(j0 + t) * ATOMF + f] = acc[t] * scale_s[t];
}

extern "C" void kernel_launch(void* const* d_in, const int* in_sizes, int n_in,
                              void* d_out, int out_size, void* d_ws, size_t ws_size,
                              hipStream_t stream) {
    const float* atom_fea = (const float*)d_in[0];
    const float* nbr_fea  = (const float*)d_in[1];
    const int*   nbr_idx  = (const int*)d_in[2];    // harness delivers integer inputs as int32
    const float* w1       = (const float*)d_in[3];
    const float* b1       = (const float*)d_in[4];
    const float* w2       = (const float*)d_in[5];
    const float* b2       = (const float*)d_in[6];
    const float* tp_w     = (const float*)d_in[7];
    float* out = (float*)d_out;

    float* S  = (float*)d_ws;       // per-atom scalar sum
    float* Cc = S + NATOM;          // per-atom edge count

    hipMemsetAsync(d_ws, 0, 2 * NATOM * sizeof(float), stream);

    edge_kernel<<<2048, 256, 0, stream>>>(nbr_fea, nbr_idx, w1, b1, w2, b2, S, Cc);
    atom_kernel<<<NATOM / 16, 128, 0, stream>>>(atom_fea, tp_w, S, Cc, out);
}

// Round 3
// 630.643 us; speedup vs baseline: 1.1796x; 1.1796x over previous
//
#include <hip/hip_runtime.h>
#include <hip/hip_bf16.h>

#define NATOM 50000
#define MNBR  32
#define NEDGE (NATOM * MNBR)   // 1,600,000 (divisible by 16)
#define ATOMF 128
#define NBRF  64
#define SHDIM 9

typedef float  f32x4  __attribute__((ext_vector_type(4)));
typedef __bf16 bf16x8 __attribute__((ext_vector_type(8)));

// Native-op softplus: max(x,0) + ln2 * log2(1 + exp2(-|x|*log2e)).
// v_exp_f32/v_log_f32 are ~2-ULP; error invisible under bf16 matmul noise.
__device__ __forceinline__ float softplus_f(float x) {
    float e = __builtin_amdgcn_exp2f(-fabsf(x) * 1.44269504089f);
    float l = __builtin_amdgcn_logf(1.0f + e);   // log2
    return fmaxf(x, 0.0f) + 0.69314718056f * l;
}

__device__ __forceinline__ bf16x8 to_bf16x8(float4 lo, float4 hi) {
    bf16x8 r;
    r[0] = (__bf16)lo.x; r[1] = (__bf16)lo.y; r[2] = (__bf16)lo.z; r[3] = (__bf16)lo.w;
    r[4] = (__bf16)hi.x; r[5] = (__bf16)hi.y; r[6] = (__bf16)hi.z; r[7] = (__bf16)hi.w;
    return r;
}

// Edge kernel: per edge e, scalar_e = softplus(nbr_fea_e @ w1 + b1) . w2[:,0] + b2[0]
// scatter-add scalar_e into S[idx_e] and 1.0 into C[idx_e].
// One wave per 16-edge tile via mfma_f32_16x16x32_bf16; w1 fragments live in
// registers for the kernel lifetime.
__global__ __launch_bounds__(256, 4) void edge_kernel(
    const float* __restrict__ nbr_fea, const int* __restrict__ nbr_idx,
    const float* __restrict__ w1, const float* __restrict__ b1,
    const float* __restrict__ w2, const float* __restrict__ b2,
    float* __restrict__ S, float* __restrict__ C)
{
    const int lane = threadIdx.x & 63;
    const int m    = lane & 15;    // A-row index (edge) / D-col index (feature)
    const int quad = lane >> 4;    // k-block / D-row-block index
    const int wave_id = (int)((blockIdx.x * blockDim.x + threadIdx.x) >> 6);
    const int nwaves  = (int)((gridDim.x * blockDim.x) >> 6);

    // B fragments: B[k][n] = w1[k][n]; lane holds k = c*32 + quad*8 + j, n = nb*16 + m
    bf16x8 bfrag[2][4];
#pragma unroll
    for (int c = 0; c < 2; ++c)
#pragma unroll
        for (int nb = 0; nb < 4; ++nb)
#pragma unroll
            for (int j = 0; j < 8; ++j)
                bfrag[c][nb][j] = (__bf16)w1[(c * 32 + quad * 8 + j) * NBRF + nb * 16 + m];

    float b1v[4], w2v[4];
#pragma unroll
    for (int nb = 0; nb < 4; ++nb) {
        b1v[nb] = b1[nb * 16 + m];
        w2v[nb] = w2[(nb * 16 + m) * SHDIM + 0];  // w2 is (64,9) row-major; col 0
    }
    const float b2_0 = b2[0];

    const int ntiles = NEDGE / 16;
    for (int t = wave_id; t < ntiles; t += nwaves) {
        const int e0 = t * 16;

        // A fragments: A[m][k], k = c*32 + quad*8 + j  -> two float4 loads per chunk
        bf16x8 afrag[2];
#pragma unroll
        for (int c = 0; c < 2; ++c) {
            const float* base = &nbr_fea[(size_t)(e0 + m) * NBRF + c * 32 + quad * 8];
            const float4 f0 = *(const float4*)(base);
            const float4 f1 = *(const float4*)(base + 4);
            afrag[c] = to_bf16x8(f0, f1);
        }

        f32x4 acc[4] = { {0.f,0.f,0.f,0.f}, {0.f,0.f,0.f,0.f},
                         {0.f,0.f,0.f,0.f}, {0.f,0.f,0.f,0.f} };
#pragma unroll
        for (int c = 0; c < 2; ++c)
#pragma unroll
            for (int nb = 0; nb < 4; ++nb)
                acc[nb] = __builtin_amdgcn_mfma_f32_16x16x32_bf16(
                    afrag[c], bfrag[c][nb], acc[nb], 0, 0, 0);

        // D layout: col(feature) = nb*16 + m, row(edge-local) = quad*4 + reg
        float part[4] = {0.f, 0.f, 0.f, 0.f};
#pragma unroll
        for (int nb = 0; nb < 4; ++nb)
#pragma unroll
            for (int r = 0; r < 4; ++r)
                part[r] += softplus_f(acc[nb][r] + b1v[nb]) * w2v[nb];

        // reduce over the 16 lanes of the quad (feature dimension)
#pragma unroll
        for (int off = 1; off < 16; off <<= 1)
#pragma unroll
            for (int r = 0; r < 4; ++r)
                part[r] += __shfl_xor(part[r], off, 64);

        if (m == 0) {
#pragma unroll
            for (int r = 0; r < 4; ++r) {
                const int e = e0 + quad * 4 + r;
                int j = nbr_idx[e];
                j = (j < 0) ? 0 : (j >= NATOM ? NATOM - 1 : j);  // never fault
                atomicAdd(&S[j], part[r] + b2_0);
                atomicAdd(&C[j], 1.0f);
            }
        }
    }
}

// Atom kernel: out[j][f] = (atom_fea[j] @ tp_w)[f] * S[j] / max(C[j],1) / sqrt(128)
// bf16 MFMA GEMM: one block (4 waves) per 16-atom tile, wave w owns features
// [w*32, w*32+32); tp_w fragments register-resident across the grid-stride loop.
__global__ __launch_bounds__(256) void atom_kernel(
    const float* __restrict__ atom_fea, const float* __restrict__ tp_w,
    const float* __restrict__ S, const float* __restrict__ C,
    float* __restrict__ out)
{
    const int lane = threadIdx.x & 63;
    const int wave = threadIdx.x >> 6;   // feature half-block: nb_global = wave*2 + nb
    const int m    = lane & 15;
    const int quad = lane >> 4;

    // B fragments: B[k][n] = tp_w[k][n]; k = c*32 + quad*8 + j, n = (wave*2+nb)*16 + m
    bf16x8 bfrag[4][2];
#pragma unroll
    for (int c = 0; c < 4; ++c)
#pragma unroll
        for (int nb = 0; nb < 2; ++nb)
#pragma unroll
            for (int j = 0; j < 8; ++j)
                bfrag[c][nb][j] =
                    (__bf16)tp_w[(c * 32 + quad * 8 + j) * ATOMF + (wave * 2 + nb) * 16 + m];

    const int ntiles = NATOM / 16;  // 3125
    for (int t = blockIdx.x; t < ntiles; t += gridDim.x) {
        const int j0 = t * 16;

        // A fragments: A[m][k] = atom_fea[j0+m][k]
        bf16x8 afrag[4];
#pragma unroll
        for (int c = 0; c < 4; ++c) {
            const float* base = &atom_fea[(size_t)(j0 + m) * ATOMF + c * 32 + quad * 8];
            const float4 f0 = *(const float4*)(base);
            const float4 f1 = *(const float4*)(base + 4);
            afrag[c] = to_bf16x8(f0, f1);
        }

        f32x4 acc[2] = { {0.f,0.f,0.f,0.f}, {0.f,0.f,0.f,0.f} };
#pragma unroll
        for (int c = 0; c < 4; ++c)
#pragma unroll
            for (int nb = 0; nb < 2; ++nb)
                acc[nb] = __builtin_amdgcn_mfma_f32_16x16x32_bf16(
                    afrag[c], bfrag[c][nb], acc[nb], 0, 0, 0);

        // scales for rows quad*4 + r
        float sc[4];
#pragma unroll
        for (int r = 0; r < 4; ++r) {
            const int j = j0 + quad * 4 + r;
            sc[r] = S[j] / fmaxf(C[j], 1.0f) * 0.08838834764831843f;  // 1/sqrt(128)
        }

#pragma unroll
        for (int nb = 0; nb < 2; ++nb)
#pragma unroll
            for (int r = 0; r < 4; ++r)
                out[(size_t)(j0 + quad * 4 + r) * ATOMF + (wave * 2 + nb) * 16 + m] =
                    acc[nb][r] * sc[r];
    }
}

extern "C" void kernel_launch(void* const* d_in, const int* in_sizes, int n_in,
                              void* d_out, int out_size, void* d_ws, size_t ws_size,
                              hipStream_t stream) {
    const float* atom_fea = (const float*)d_in[0];
    const float* nbr_fea  = (const float*)d_in[1];
    const int*   nbr_idx  = (const int*)d_in[2];    // harness delivers integer inputs as int32
    const float* w1       = (const float*)d_in[3];
    const float* b1       = (const float*)d_in[4];
    const float* w2       = (const float*)d_in[5];
    const float* b2       = (const float*)d_in[6];
    const float* tp_w     = (const float*)d_in[7];
    float* out = (float*)d_out;

    float* S  = (float*)d_ws;       // per-atom scalar sum
    float* Cc = S + NATOM;          // per-atom edge count

    hipMemsetAsync(d_ws, 0, 2 * NATOM * sizeof(float), stream);

    edge_kernel<<<2048, 256, 0, stream>>>(nbr_fea, nbr_idx, w1, b1, w2, b2, S, Cc);
    atom_kernel<<<1024, 256, 0, stream>>>(atom_fea, tp_w, S, Cc, out);
}